// Round 5
// baseline (506.410 us; speedup 1.0000x reference)
//
#include <hip/hip_runtime.h>
#include <math.h>
#include <stdint.h>

#define B_  16
#define T_  4096
#define D_  512
#define M_  256
#define TP_ 4098   // T + 2 causal pad rows (granule-column-major padded hidden layout)

// output element offsets (float elements, concatenated in reference return order)
static constexpr long O_RATE = 0;          // [B,1]
static constexpr long O_ZOP  = 16;         // [B,8]
static constexpr long O_RVAL = 144;        // [B,M]
static constexpr long O_RVAR = 4240;       // [B,M]
static constexpr long O_RCOV = 8336;       // [B,M]
static constexpr long O_MASK = 12432;      // [B,T]
static constexpr long O_LOGD = 77968;      // [B,T]
static constexpr long O_RESID= 143504;     // [B,T]
static constexpr long O_ATTN = 209040;     // [B,T,M]
static constexpr long O_FIT  = 16986256;   // [B,T]

typedef unsigned short u16;
typedef unsigned int u32;
typedef __attribute__((ext_vector_type(8))) __bf16 bf16x8;
typedef __attribute__((ext_vector_type(4))) float fx4;

__device__ __forceinline__ float b2f(u16 u){ union{float f;uint32_t i;}v; v.i=((uint32_t)u)<<16; return v.f; }
__device__ __forceinline__ u16 f2b(float f){ union{float f;uint32_t i;}v; v.f=f; uint32_t r=v.i+0x7fffu+((v.i>>16)&1u); return (u16)(r>>16); }
__device__ __forceinline__ float clip01(float x){ return fminf(fmaxf(x, 0.f), 1.f); }
__device__ __forceinline__ float gelu_f(float x){ return 0.5f*x*(1.0f+erff(x*0.70710678118654752440f)); }

__device__ __forceinline__ void cp16(const u16* g, u16* l){
  __builtin_amdgcn_global_load_lds((__attribute__((address_space(1))) void*)g,
                                   (__attribute__((address_space(3))) void*)l, 16, 0, 0);
}

// hidden layout: granule(b,g,t) at ((b*64+g)*TP_ + t), 8 u16 each.

// ---------------- init: zero pads of h0 & hA, zero_operator -----------------
__global__ void k_init(u16* __restrict__ h0, u16* __restrict__ hA, int Cloc,
                       float* __restrict__ out){
  int i = blockIdx.x*256 + threadIdx.x;
  int nA = Cloc << 7;                       // h0 pad granules: C*64g*2t
  if (i < nA){
    int lb = i >> 7, r = i & 127, g = r >> 1, t = r & 1;
    *(uint4*)(h0 + ((long)(lb*64 + g)*TP_ + t)*8) = make_uint4(0,0,0,0);
  } else if (i < nA + 2048){
    int j = i - nA;
    int b = j >> 7, r = j & 127, g = r >> 1, t = r & 1;
    *(uint4*)(hA + ((long)(b*64 + g)*TP_ + t)*8) = make_uint4(0,0,0,0);
  } else if (i < nA + 2048 + 128){
    out[O_ZOP + (i - nA - 2048)] = 0.f;
  }
}

// ---- repack: conv weights -> pre-tiled bf16 [conv][tap][kt][g][row512];
//      role_key -> bf16 (gain-folded) pre-tiled [kt][g][row256]
__global__ void k_repack(const float* __restrict__ w1, const float* __restrict__ w2,
                         const float* __restrict__ rk, const float* __restrict__ lng,
                         u16* __restrict__ wrp2, u16* __restrict__ rkb){
  int i = blockIdx.x*256 + threadIdx.x;       // 1572864 + 131072
  if (i < 1572864){
    int gi = i >> 3, c7 = i & 7;
    int row = gi & 511;                 // out channel
    int g   = (gi >> 9) & 3;
    int kt  = (gi >> 11) & 15;
    int tg  = gi >> 15;                 // 0..5
    int conv = tg / 3, tap = tg % 3;
    int ic = kt*32 + g*8 + c7;
    const float* w = conv ? w2 : w1;
    wrp2[i] = f2b(w[(row*512 + ic)*3 + tap]);
  } else {
    int j = i - 1572864;
    int gi = j >> 3, c7 = j & 7;
    int n  = gi & 255;
    int g  = (gi >> 8) & 3;
    int kt = gi >> 10;
    int k  = kt*32 + g*8 + c7;
    rkb[j] = f2b(rk[n*512 + k] * lng[k]);
  }
}

// ---- GB[n] = sum_k g[k]*key[n,k]; BeB[n] = sum_k be[k]*key[n,k] ------------
__global__ __launch_bounds__(64) void k_gbb(const float* __restrict__ rk,
                                            const float* __restrict__ lng,
                                            const float* __restrict__ lnb,
                                            float* __restrict__ GB,
                                            float* __restrict__ BeB){
  int n = blockIdx.x, lane = threadIdx.x;
  float sg = 0.f, sb = 0.f;
  #pragma unroll
  for (int j = 0; j < 8; ++j){
    int k = lane*8 + j;
    float kv = rk[(long)n*512 + k];
    sg += lng[k]*kv; sb += lnb[k]*kv;
  }
  #pragma unroll
  for (int d=1; d<64; d<<=1){ sg += __shfl_xor(sg, d); sb += __shfl_xor(sb, d); }
  if (lane == 0){ GB[n] = sg; BeB[n] = sb; }
}

// ---------------- per-batch: mask/logdur outputs, exact lower median --------
__global__ __launch_bounds__(1024) void k_median(
    const float* __restrict__ dur, const float* __restrict__ msk,
    float* __restrict__ out, float* __restrict__ supp_f){
  __shared__ u32 keys[4096];
  __shared__ u32 hist[2048];
  __shared__ float sred[1024];
  __shared__ u32 selBin, selRank;
  __shared__ float sMed;
  const int tid = threadIdx.x;
  const int b = blockIdx.x;
  float msum = 0.f;
  for (int i = tid; i < 4096; i += 1024){
    int bt = (b << 12) + i;
    float m  = clip01(msk[bt]);
    float ld = logf(fmaxf(dur[bt], 1e-4f)) * m;
    out[O_MASK + bt] = m;
    out[O_LOGD + bt] = ld;
    u32 u = __float_as_uint(ld);
    u32 k = (u & 0x80000000u) ? ~u : (u | 0x80000000u);
    keys[i] = (m > 0.5f) ? k : 0xFFFFFFFFu;
    msum += m;
  }
  sred[tid] = msum;
  __syncthreads();
  for (int s = 512; s > 0; s >>= 1){
    if (tid < s) sred[tid] += sred[tid + s];
    __syncthreads();
  }
  float msumT = sred[0];
  int cnt = (int)(msumT + 0.5f);
  u32 prefix = 0;
  u32 r = (cnt > 0) ? (u32)((cnt - 1) >> 1) : 0u;
  if (cnt > 0){
    #pragma unroll
    for (int p = 0; p < 3; ++p){
      const int shift = (p==0) ? 21 : (p==1) ? 10 : 0;
      const int nb = (p==2) ? 1024 : 2048;
      const u32 himask = (p==0) ? 0u : (0xFFFFFFFFu << (shift + ((p==2)?10:11)));
      hist[tid] = 0u; hist[tid + 1024] = 0u;
      __syncthreads();
      for (int i = tid; i < 4096; i += 1024){
        u32 k = keys[i];
        if ((k & himask) == prefix)
          atomicAdd(&hist[(k >> shift) & (u32)(nb-1)], 1u);
      }
      __syncthreads();
      if (tid < 64){
        u32 lane = tid;
        u32 cum = 0;
        for (int chunk = 0; chunk < nb/64; ++chunk){
          u32 v = hist[chunk*64 + lane];
          u32 incl = v;
          #pragma unroll
          for (int d = 1; d < 64; d <<= 1){
            u32 o = __shfl_up(incl, d);
            if (lane >= (u32)d) incl += o;
          }
          u32 total = __shfl(incl, 63);
          if (r < cum + total){
            u32 excl = incl - v;
            bool hit = (r >= cum + excl) && (r < cum + excl + v);
            unsigned long long bal = __ballot(hit);
            int L = __ffsll((unsigned long long)bal) - 1;
            u32 exclL = __shfl(excl, L);
            if (lane == 0){ selBin = (u32)(chunk*64 + L); selRank = r - (cum + exclL); }
            break;
          }
          cum += total;
        }
      }
      __syncthreads();
      prefix |= (selBin << shift);
      r = selRank;
      __syncthreads();
    }
  }
  if (tid == 0){
    float med = 0.f;
    if (cnt > 0){
      u32 k = prefix;
      u32 u = (k & 0x80000000u) ? (k ^ 0x80000000u) : ~k;
      med = __uint_as_float(u);
    }
    out[O_RATE + b] = med;
    supp_f[b] = fmaxf(msumT, 1.0f);
    sMed = med;
  }
  __syncthreads();
  float med = sMed;
  for (int i = tid; i < 4096; i += 1024){
    int bt = (b << 12) + i;
    float m  = clip01(msk[bt]);
    float ld = logf(fmaxf(dur[bt], 1e-4f)) * m;
    out[O_RESID + bt] = (ld - med) * m;
  }
}

// ---------------- embedding + aux proj -> h0 [g][t] (coalesced writes) ------
__global__ __launch_bounds__(256) void k_embed(
    const int* __restrict__ units, const float* __restrict__ dur,
    const float* __restrict__ msk, const float* __restrict__ emb,
    const float* __restrict__ pw, const float* __restrict__ pb,
    u16* __restrict__ h0, int b0){
  int wid = threadIdx.x >> 6, lane = threadIdx.x & 63;
  int w = blockIdx.x*4 + wid;           // over C*64g*64tb
  int tb = w & 63, g = (w >> 6) & 63, lb = w >> 12;
  int t = tb*64 + lane;
  int bt = ((b0 + lb) << 12) + t;
  float m = clip01(msk[bt]);
  float ld = logf(fmaxf(dur[bt], 1e-4f)) * m;
  long u = units[bt];
  const float* er = emb + u*512 + g*8;
  float4 e0 = *(const float4*)er;
  float4 e1 = *(const float4*)(er + 4);
  float x[8] = {e0.x,e0.y,e0.z,e0.w,e1.x,e1.y,e1.z,e1.w};
  union { u16 s[8]; uint4 v; } o;
  #pragma unroll
  for (int j=0;j<8;++j)
    o.s[j] = f2b(x[j] + ld*pw[(g*8+j)*4] + pb[g*8+j]);
  *(uint4*)(h0 + ((long)(lb*64 + g)*TP_ + 2 + t)*8) = o.v;
}

// ---------------- causal conv (K=3) MFMA GEMM (R1-proven structure) ---------
// 256x256 tile, 8 waves (2M x 4N), BK = 32 channels x 3 taps.
// LDS double-buffered, one-K-step-ahead prefetch via global_load_lds with
// counted s_waitcnt vmcnt(8) (never 0 in steady state) + raw s_barrier.
// LDS granule map: A0 [0,1032) A1 [1032,2064) B0 [2064,5184) B1 [5184,8304)
// A: [gcol4][row258]; B: [tap3][g4][col256 pad->260] (g-stride 260 granules
// = 4160B = 16-bank shift: 4-way read conflict -> free 2-way; was bank 0).
__device__ __forceinline__ void stageA(u16* smem, const u16* hin, long aG, int t0,
                                       int tid, int kt, int base){
  #pragma unroll
  for (int q = 0; q < 2; ++q){
    int s = q*512 + tid;
    int gl = s / 258, row = s - gl*258;
    cp16(hin + (aG + (long)(kt*4 + gl)*TP_ + t0 + row)*8, &smem[(base + s)*8]);
  }
  if (tid < 8){
    int s = 1024 + tid;                       // gl = 3, row = s - 774
    cp16(hin + (aG + (long)(kt*4 + 3)*TP_ + t0 + (s - 774))*8, &smem[(base + s)*8]);
  }
}
__device__ __forceinline__ void stageB(u16* smem, const u16* w, int n0,
                                       int tid, int kt, int base){
  #pragma unroll
  for (int q = 0; q < 6; ++q){
    int s2 = q*512 + tid;
    int tap = s2 >> 10, g = (s2 >> 8) & 3, col = s2 & 255;
    // per-wave dest stays 64-granule contiguous within one (tap,g) section
    cp16(w + ((long)((tap*16 + kt)*4 + g)*512 + n0 + col)*8,
         &smem[(base + tap*1040 + g*260 + col)*8]);
  }
}

template<int STATS>
__global__ __launch_bounds__(512, 2) void k_conv(const u16* __restrict__ hin,
                                                 const u16* __restrict__ wrp2c,
                                                 const float* __restrict__ bias,
                                                 u16* __restrict__ hout,
                                                 float* __restrict__ rsum,
                                                 float* __restrict__ rsumsq,
                                                 int statsBase, int nwg){
  __shared__ __align__(16) u16 smem[66432];   // 8304 granules (132,864 B)
  const int tid = threadIdx.x;
  const int lane = tid & 63, wid = tid >> 6;
  const int wm = wid >> 2, wn = wid & 3;      // 2M x 4N waves
  const int g4 = lane >> 4, r16 = lane & 15;
  // XCD-chunked bijective swizzle (nwg % 8 == 0 always: nwg = C*32)
  const int cpx = nwg >> 3;
  const int wg  = ((int)blockIdx.x & 7)*cpx + ((int)blockIdx.x >> 3);
  const int nt = wg & 1, mt = wg >> 1;
  const int lb = mt >> 4, t0 = (mt & 15) << 8;
  const int n0 = nt << 8;
  const long aG = (long)lb*64*TP_;

  fx4 acc[8][4];
  #pragma unroll
  for (int i=0;i<8;++i)
    #pragma unroll
    for (int j=0;j<4;++j){ acc[i][j][0]=0.f; acc[i][j][1]=0.f; acc[i][j][2]=0.f; acc[i][j][3]=0.f; }

  // prologue: stage kt=0 into buffer 0 (B first, then A — matches in-loop order)
  stageB(smem, wrp2c, n0, tid, 0, 2064);
  stageA(smem, hin, aG, t0, tid, 0, 0);

  int cur = 0;
  #pragma unroll 1
  for (int kt = 0; kt < 16; ++kt){
    if (kt < 15){
      // issue next K-step stages (B: 6/thread from L2; A: 2-3/thread from HBM)
      stageB(smem, wrp2c, n0, tid, kt+1, 2064 + (cur^1)*3120);
      stageA(smem, hin, aG, t0, tid, kt+1, (cur^1)*1032);
      // drain previous tile's loads; keep this iteration's 8 newest in flight
      asm volatile("s_waitcnt vmcnt(8)" ::: "memory");
    } else {
      asm volatile("s_waitcnt vmcnt(0)" ::: "memory");
    }
    __builtin_amdgcn_s_barrier();
    __builtin_amdgcn_sched_barrier(0);
    {
      const u16* Ab = &smem[cur*1032*8];
      const u16* Bb = &smem[(2064 + cur*3120)*8];
      #pragma unroll
      for (int tap = 0; tap < 3; ++tap){
        bf16x8 af[8], bf[4];
        #pragma unroll
        for (int mi=0;mi<8;++mi)
          af[mi] = *(const bf16x8*)&Ab[(g4*258 + wm*128 + mi*16 + r16 + tap)*8];
        #pragma unroll
        for (int ni=0;ni<4;++ni)
          bf[ni] = *(const bf16x8*)&Bb[(tap*1040 + g4*260 + wn*64 + ni*16 + r16)*8];
        __builtin_amdgcn_s_setprio(1);
        #pragma unroll
        for (int mi=0;mi<8;++mi)
          #pragma unroll
          for (int ni=0;ni<4;++ni)
            acc[mi][ni] = __builtin_amdgcn_mfma_f32_16x16x32_bf16(af[mi], bf[ni], acc[mi][ni], 0,0,0);
        __builtin_amdgcn_s_setprio(0);
      }
    }
    __builtin_amdgcn_sched_barrier(0);
    __builtin_amdgcn_s_barrier();
    cur ^= 1;
  }

  // epilogue: bias + gelu (+stats), then LDS transpose -> coalesced [g][t] stores
  __builtin_amdgcn_sched_barrier(0);
  const int cl = r16;
  float bv[4];
  #pragma unroll
  for (int ni=0;ni<4;++ni) bv[ni] = bias[n0 + wn*64 + ni*16 + cl];
  #pragma unroll
  for (int mi=0;mi<8;++mi)
    #pragma unroll
    for (int rg=0;rg<4;++rg){
      int r = wm*128 + mi*16 + g4*4 + rg;
      float sv = 0.f, sv2 = 0.f;
      #pragma unroll
      for (int ni=0;ni<4;++ni){
        float v = gelu_f(acc[mi][ni][rg] + bv[ni]);
        int c = wn*64 + ni*16 + cl;
        smem[(c >> 3)*2048 + r*8 + (c & 7)] = f2b(v);
        if (STATS){ sv += v; sv2 += v*v; }
      }
      if (STATS){
        #pragma unroll
        for (int d=1; d<16; d<<=1){ sv += __shfl_xor(sv, d); sv2 += __shfl_xor(sv2, d); }
        if (cl == 0){
          int grow = statsBase + lb*4096 + t0 + r;
          atomicAdd(&rsum[grow], sv);
          atomicAdd(&rsumsq[grow], sv2);
        }
      }
    }
  __syncthreads();
  #pragma unroll
  for (int it = 0; it < 16; ++it){
    int s = it*512 + tid;
    int gc = s >> 8, row = s & 255;
    long gran = aG + (long)(nt*32 + gc)*TP_ + 2 + t0 + row;
    *(uint4*)(hout + gran*8) = *(const uint4*)&smem[gc*2048 + row*8];
  }
}

// -------- score GEMM (LN fused as affine) + softmax + attn + S-reductions ---
// 512 thr / 8 waves (2M x 4N, wave = 64x64), double-buffered A+B staging,
// counted vmcnt(3), setprio, XCD swizzle. A/B LDS strides padded (130/260
// granules) to break 4-way bank conflicts. Attn output staged through a
// padded fp32 LDS buffer -> fully-coalesced float4 stores (1KB/wave).
__global__ __launch_bounds__(512, 4) void k_score(const u16* __restrict__ h,
                                                  const u16* __restrict__ rkb,
                                                  const float* __restrict__ msk,
                                                  const float* __restrict__ rsum,
                                                  const float* __restrict__ rsumsq,
                                                  const float* __restrict__ GB,
                                                  const float* __restrict__ BeB,
                                                  float* __restrict__ S0,
                                                  float* __restrict__ S1,
                                                  float* __restrict__ S2,
                                                  float* __restrict__ out, int b0){
  __shared__ __align__(16) u16 smem[24960];   // 3120 granules: A 2x520, B 2x1040
  __shared__ float smax[128][4];
  __shared__ float ssum[128][4];
  const int tid = threadIdx.x;
  const int lane = tid & 63, wid = tid >> 6;
  const int wm = wid >> 2, wn = wid & 3;      // 2M x 4N waves
  const int g4 = lane >> 4, r16 = lane & 15;
  // XCD-chunked bijective swizzle over row-tiles (gridDim.x % 8 == 0)
  const int cpx = (int)gridDim.x >> 3;
  const int wg  = ((int)blockIdx.x & 7)*cpx + ((int)blockIdx.x >> 3);
  const int r0 = wg << 7;
  const int lb = r0 >> 12, t0 = r0 & 4095;
  const int gb = b0 + lb;
  const long gRow0 = ((long)gb << 12) + t0;
  const long aG = (long)lb*64*TP_;

  fx4 acc[4][4];
  #pragma unroll
  for (int i=0;i<4;++i)
    #pragma unroll
    for (int j=0;j<4;++j){ acc[i][j][0]=0.f; acc[i][j][1]=0.f; acc[i][j][2]=0.f; acc[i][j][3]=0.f; }

  // stage tile kt into buffer buf: A 1/thread + B 2/thread = 3 VMEM per thread
  // A lds: [g4][row128 pad->130]; B lds: [g4][col256 pad->260]
  #define SC_STAGE(kt, buf) do {                                               \
    int s = tid; int gl = s >> 7, row = s & 127;                               \
    cp16(h + (aG + (long)((kt)*4 + gl)*TP_ + 2 + t0 + row)*8,                  \
         &smem[((buf)*520 + gl*130 + row)*8]);                                 \
    _Pragma("unroll")                                                          \
    for (int q = 0; q < 2; ++q){                                               \
      int s2 = q*512 + tid;                                                    \
      int g = s2 >> 8, col = s2 & 255;                                         \
      cp16(rkb + ((long)(kt)*1024 + s2)*8,                                     \
           &smem[(1040 + (buf)*1040 + g*260 + col)*8]);                        \
    } } while(0)

  SC_STAGE(0, 0);
  #pragma unroll 1
  for (int kt = 0; kt < 16; ++kt){
    const int cur = kt & 1;
    if (kt < 15){
      SC_STAGE(kt+1, cur^1);
      asm volatile("s_waitcnt vmcnt(3)" ::: "memory");
    } else {
      asm volatile("s_waitcnt vmcnt(0)" ::: "memory");
    }
    __builtin_amdgcn_s_barrier();
    __builtin_amdgcn_sched_barrier(0);
    {
      const u16* Ab = &smem[(cur*520)*8];
      const u16* Bb = &smem[(1040 + cur*1040)*8];
      bf16x8 af[4], bf[4];
      #pragma unroll
      for (int mi=0;mi<4;++mi)
        af[mi] = *(const bf16x8*)&Ab[(g4*130 + wm*64 + mi*16 + r16)*8];
      #pragma unroll
      for (int ni=0;ni<4;++ni)
        bf[ni] = *(const bf16x8*)&Bb[(g4*260 + wn*64 + ni*16 + r16)*8];
      __builtin_amdgcn_s_setprio(1);
      #pragma unroll
      for (int mi=0;mi<4;++mi)
        #pragma unroll
        for (int ni=0;ni<4;++ni)
          acc[mi][ni] = __builtin_amdgcn_mfma_f32_16x16x32_bf16(af[mi], bf[ni], acc[mi][ni], 0,0,0);
      __builtin_amdgcn_s_setprio(0);
    }
    __builtin_amdgcn_sched_barrier(0);
    __builtin_amdgcn_s_barrier();
  }
  #undef SC_STAGE

  const float SCALE = 0.044194173824159216f;   // 1/sqrt(512)
  const int cl = r16;
  float gbv[4], bbv[4];
  #pragma unroll
  for (int ni=0;ni<4;++ni){
    int col = wn*64 + ni*16 + cl;
    gbv[ni] = GB[col]; bbv[ni] = BeB[col];
  }
  float gmx[4][4];
  #pragma unroll
  for (int mi=0;mi<4;++mi)
    #pragma unroll
    for (int rg=0;rg<4;++rg){
      int row = wm*64 + mi*16 + g4*4 + rg;
      long gRow = gRow0 + row;
      float mk = clip01(msk[gRow]);
      float mu = rsum[gRow] * (1.f/512.f);
      float var = rsumsq[gRow] * (1.f/512.f) - mu*mu;
      float inv = rsqrtf(var + 1e-5f);
      float mx = -1e30f;
      #pragma unroll
      for (int ni=0;ni<4;++ni){
        float s = mk * SCALE * (inv*(acc[mi][ni][rg] - mu*gbv[ni]) + bbv[ni]);
        acc[mi][ni][rg] = s;
        mx = fmaxf(mx, s);
      }
      #pragma unroll
      for (int d=1; d<16; d<<=1) mx = fmaxf(mx, __shfl_xor(mx, d));
      if (cl == 0) smax[row][wn] = mx;
    }
  __syncthreads();
  #pragma unroll
  for (int mi=0;mi<4;++mi)
    #pragma unroll
    for (int rg=0;rg<4;++rg){
      int row = wm*64 + mi*16 + g4*4 + rg;
      gmx[mi][rg] = fmaxf(fmaxf(smax[row][0], smax[row][1]),
                          fmaxf(smax[row][2], smax[row][3]));
    }
  #pragma unroll
  for (int mi=0;mi<4;++mi)
    #pragma unroll
    for (int rg=0;rg<4;++rg){
      float s = 0.f;
      #pragma unroll
      for (int ni=0;ni<4;++ni){
        float e = expf(acc[mi][ni][rg] - gmx[mi][rg]);
        acc[mi][ni][rg] = e;
        s += e;
      }
      #pragma unroll
      for (int d=1; d<16; d<<=1) s += __shfl_xor(s, d);
      if (cl == 0) ssum[wm*64 + mi*16 + g4*4 + rg][wn] = s;
    }
  __syncthreads();
  // ---- attn epilogue: per-mi 32x256 chunk through padded LDS fp32 buffer ---
  float* fbuf = (float*)smem;                 // 32 x 260 floats = 33,280 B
  float ps0[4], ps1[4], ps2[4];
  #pragma unroll
  for (int ni=0;ni<4;++ni){ ps0[ni]=0.f; ps1[ni]=0.f; ps2[ni]=0.f; }
  #pragma unroll
  for (int mi=0;mi<4;++mi){
    __syncthreads();                          // fbuf free (prev flush done)
    #pragma unroll
    for (int rg=0;rg<4;++rg){
      int row = wm*64 + mi*16 + g4*4 + rg;
      long gRow = gRow0 + row;
      float tot = (ssum[row][0] + ssum[row][1]) + (ssum[row][2] + ssum[row][3]);
      float mk = clip01(msk[gRow]);
      float f = mk / tot;
      float rr = out[O_RESID + gRow];
      #pragma unroll
      for (int ni=0;ni<4;++ni){
        float a = acc[mi][ni][rg] * f;
        fbuf[(wm*16 + g4*4 + rg)*260 + wn*64 + ni*16 + cl] = a;
        ps0[ni] += a; ps1[ni] += a*rr; ps2[ni] += a*rr*rr;
      }
    }
    __syncthreads();
    #pragma unroll
    for (int p=0;p<4;++p){
      int lrow = p*8 + (tid >> 6);            // one row per wave per pass
      int c4 = tid & 63;
      float4 v = *(const float4*)&fbuf[lrow*260 + c4*4];
      int grow = (lrow >> 4)*64 + mi*16 + (lrow & 15);
      *(float4*)(out + O_ATTN + (gRow0 + grow)*M_ + c4*4) = v;
    }
  }
  #pragma unroll
  for (int ni=0;ni<4;++ni){
    ps0[ni] += __shfl_xor(ps0[ni], 16); ps0[ni] += __shfl_xor(ps0[ni], 32);
    ps1[ni] += __shfl_xor(ps1[ni], 16); ps1[ni] += __shfl_xor(ps1[ni], 32);
    ps2[ni] += __shfl_xor(ps2[ni], 16); ps2[ni] += __shfl_xor(ps2[ni], 32);
  }
  if (g4 == 0){
    #pragma unroll
    for (int ni=0;ni<4;++ni){
      int col = wn*64 + ni*16 + cl;
      atomicAdd(&S0[gb*M_ + col], ps0[ni]);
      atomicAdd(&S1[gb*M_ + col], ps1[ni]);
      atomicAdd(&S2[gb*M_ + col], ps2[ni]);
    }
  }
}

// ---------------- finalize role_value / role_var / role_cov -----------------
__global__ __launch_bounds__(256) void k_final(const float* __restrict__ S0,
                                               const float* __restrict__ S1,
                                               const float* __restrict__ S2,
                                               const float* __restrict__ supp,
                                               float* __restrict__ out,
                                               float* __restrict__ rvf){
  int i = blockIdx.x*256 + threadIdx.x;   // 4096
  int b = i >> 8;
  float s0 = S0[i], s1 = S1[i], s2 = S2[i];
  float cov = fmaxf(s0, 1e-6f);
  float rv = s1 / cov;
  float var = fmaxf((s2 - 2.f*rv*s1 + rv*rv*s0) / cov, 1e-4f);
  float rc = fmaxf(cov / supp[b], 0.05f);
  out[O_RVAL + i] = rv;
  out[O_RVAR + i] = var;
  out[O_RCOV + i] = rc;
  rvf[i] = rv;
}

// ---------------- prompt_role_fit = (attn . role_value) * mask --------------
__global__ __launch_bounds__(256) void k_fit(const float* __restrict__ attn,
                                             const float* __restrict__ rvf,
                                             const float* __restrict__ msk,
                                             float* __restrict__ out){
  int wid = threadIdx.x >> 6, lane = threadIdx.x & 63;
  int row = blockIdx.x*4 + wid;
  int b = row >> 12;
  float4 a = *(const float4*)(attn + (long)row*M_ + lane*4);
  float4 r = *(const float4*)(rvf + b*M_ + lane*4);
  float dot = a.x*r.x + a.y*r.y + a.z*r.z + a.w*r.w;
  #pragma unroll
  for (int d=1; d<64; d<<=1) dot += __shfl_xor(dot, d);
  if (lane == 0) out[O_FIT + row] = dot * clip01(msk[row]);
}

// ---------------- launcher --------------------------------------------------
extern "C" void kernel_launch(void* const* d_in, const int* in_sizes, int n_in,
                              void* d_out, int out_size, void* d_ws, size_t ws_size,
                              hipStream_t stream) {
  const int*   units = (const int*)d_in[0];
  const float* dur   = (const float*)d_in[1];
  const float* msk   = (const float*)d_in[2];
  const float* emb   = (const float*)d_in[3];
  const float* pw    = (const float*)d_in[4];
  const float* pb    = (const float*)d_in[5];
  const float* w1    = (const float*)d_in[6];
  const float* b1    = (const float*)d_in[7];
  const float* w2    = (const float*)d_in[8];
  const float* b2c   = (const float*)d_in[9];
  const float* lng   = (const float*)d_in[10];
  const float* lnb   = (const float*)d_in[11];
  const float* rk    = (const float*)d_in[12];
  float* out = (float*)d_out;
  char* ws = (char*)d_ws;

  // conv1 output lives in the (dead-until-k_score) attn+fit region of d_out
  u16* hA = (u16*)(out + O_ATTN);

  const size_t perB = (size_t)64*TP_*16;               // 4,196,352 B per batch
  const size_t tail = 3145728 + 262144 + 1024 + 1024 + 64 + 16384 + 49152 + 262144 + 262144;
  int C = 16;
  while (C > 1 && ((size_t)C*perB + tail) > ws_size) C >>= 1;
  const int nch = 16 / C;

  char* p = ws;
  u16*   h0    = (u16*)p;            p += (size_t)C*perB;
  u16*   wrp2  = (u16*)p;            p += 3145728;
  u16*   rkb   = (u16*)p;            p += 262144;
  float* GB    = (float*)p;          p += 1024;
  float* BeB   = (float*)p;          p += 1024;
  float* supp_f= (float*)p;          p += 64;
  float* rv_f  = (float*)p;          p += 16384;
  float* S0    = (float*)p;          p += 49152;  // S0,S1,S2
  float* S1    = S0 + 4096;
  float* S2    = S1 + 4096;
  float* rsum  = (float*)p;          p += 262144;
  float* rsumsq= (float*)p;          p += 262144;

  hipMemsetAsync(S0, 0, 49152 + 262144 + 262144, stream);
  int initN = (C << 7) + 2048 + 128;
  k_init  <<<(initN + 255)/256, 256, 0, stream>>>(h0, hA, C, out);
  k_repack<<<6656, 256, 0, stream>>>(w1, w2, rk, lng, wrp2, rkb);
  k_gbb   <<<256,   64, 0, stream>>>(rk, lng, lnb, GB, BeB);
  k_median<<<16,  1024, 0, stream>>>(dur, msk, out, supp_f);
  const int nwg = C*32;
  for (int c = 0; c < nch; ++c){
    int b0 = c*C;
    u16* hAc = hA + (size_t)b0*64*TP_*8;
    k_embed  <<<C*1024, 256, 0, stream>>>(units, dur, msk, emb, pw, pb, h0, b0);
    k_conv<0><<<nwg,    512, 0, stream>>>(h0,  wrp2,           b1,  hAc, rsum, rsumsq, 0,       nwg);
    k_conv<1><<<nwg,    512, 0, stream>>>(hAc, wrp2 + 786432,  b2c, h0,  rsum, rsumsq, b0*4096, nwg);
    k_score  <<<nwg,    512, 0, stream>>>(h0, rkb, msk, rsum, rsumsq, GB, BeB, S0, S1, S2, out, b0);
  }
  k_final <<<16,    256, 0, stream>>>(S0, S1, S2, supp_f, out, rv_f);
  k_fit   <<<16384, 256, 0, stream>>>(out + O_ATTN, rv_f, msk, out);
}

// Round 6
// 471.760 us; speedup vs baseline: 1.0734x; 1.0734x over previous
//
#include <hip/hip_runtime.h>
#include <math.h>
#include <stdint.h>

#define B_  16
#define T_  4096
#define D_  512
#define M_  256
#define TP_ 4098   // T + 2 causal pad rows (granule-column-major padded hidden layout)

// output element offsets (float elements, concatenated in reference return order)
static constexpr long O_RATE = 0;          // [B,1]
static constexpr long O_ZOP  = 16;         // [B,8]
static constexpr long O_RVAL = 144;        // [B,M]
static constexpr long O_RVAR = 4240;       // [B,M]
static constexpr long O_RCOV = 8336;       // [B,M]
static constexpr long O_MASK = 12432;      // [B,T]
static constexpr long O_LOGD = 77968;      // [B,T]
static constexpr long O_RESID= 143504;     // [B,T]
static constexpr long O_ATTN = 209040;     // [B,T,M]
static constexpr long O_FIT  = 16986256;   // [B,T]

typedef unsigned short u16;
typedef unsigned int u32;
typedef __attribute__((ext_vector_type(8))) __bf16 bf16x8;
typedef __attribute__((ext_vector_type(4))) float fx4;

__device__ __forceinline__ float b2f(u16 u){ union{float f;uint32_t i;}v; v.i=((uint32_t)u)<<16; return v.f; }
__device__ __forceinline__ u16 f2b(float f){ union{float f;uint32_t i;}v; v.f=f; uint32_t r=v.i+0x7fffu+((v.i>>16)&1u); return (u16)(r>>16); }
__device__ __forceinline__ float clip01(float x){ return fminf(fmaxf(x, 0.f), 1.f); }
__device__ __forceinline__ float gelu_f(float x){ return 0.5f*x*(1.0f+erff(x*0.70710678118654752440f)); }

__device__ __forceinline__ void cp16(const u16* g, u16* l){
  __builtin_amdgcn_global_load_lds((__attribute__((address_space(1))) void*)g,
                                   (__attribute__((address_space(3))) void*)l, 16, 0, 0);
}

// hidden layout: granule(b,g,t) at ((b*64+g)*TP_ + t), 8 u16 each.

// ---------------- init: zero pads of h0 & hA, zero_operator -----------------
__global__ void k_init(u16* __restrict__ h0, u16* __restrict__ hA, int Cloc,
                       float* __restrict__ out){
  int i = blockIdx.x*256 + threadIdx.x;
  int nA = Cloc << 7;                       // h0 pad granules: C*64g*2t
  if (i < nA){
    int lb = i >> 7, r = i & 127, g = r >> 1, t = r & 1;
    *(uint4*)(h0 + ((long)(lb*64 + g)*TP_ + t)*8) = make_uint4(0,0,0,0);
  } else if (i < nA + 2048){
    int j = i - nA;
    int b = j >> 7, r = j & 127, g = r >> 1, t = r & 1;
    *(uint4*)(hA + ((long)(b*64 + g)*TP_ + t)*8) = make_uint4(0,0,0,0);
  } else if (i < nA + 2048 + 128){
    out[O_ZOP + (i - nA - 2048)] = 0.f;
  }
}

// ---- repack: conv weights -> pre-tiled bf16 [conv][tap][kt][g][row512];
//      role_key -> bf16 (gain-folded) pre-tiled [kt][g][row256]
__global__ void k_repack(const float* __restrict__ w1, const float* __restrict__ w2,
                         const float* __restrict__ rk, const float* __restrict__ lng,
                         u16* __restrict__ wrp2, u16* __restrict__ rkb){
  int i = blockIdx.x*256 + threadIdx.x;       // 1572864 + 131072
  if (i < 1572864){
    int gi = i >> 3, c7 = i & 7;
    int row = gi & 511;                 // out channel
    int g   = (gi >> 9) & 3;
    int kt  = (gi >> 11) & 15;
    int tg  = gi >> 15;                 // 0..5
    int conv = tg / 3, tap = tg % 3;
    int ic = kt*32 + g*8 + c7;
    const float* w = conv ? w2 : w1;
    wrp2[i] = f2b(w[(row*512 + ic)*3 + tap]);
  } else {
    int j = i - 1572864;
    int gi = j >> 3, c7 = j & 7;
    int n  = gi & 255;
    int g  = (gi >> 8) & 3;
    int kt = gi >> 10;
    int k  = kt*32 + g*8 + c7;
    rkb[j] = f2b(rk[n*512 + k] * lng[k]);
  }
}

// ---- GB[n] = sum_k g[k]*key[n,k]; BeB[n] = sum_k be[k]*key[n,k] ------------
__global__ __launch_bounds__(64) void k_gbb(const float* __restrict__ rk,
                                            const float* __restrict__ lng,
                                            const float* __restrict__ lnb,
                                            float* __restrict__ GB,
                                            float* __restrict__ BeB){
  int n = blockIdx.x, lane = threadIdx.x;
  float sg = 0.f, sb = 0.f;
  #pragma unroll
  for (int j = 0; j < 8; ++j){
    int k = lane*8 + j;
    float kv = rk[(long)n*512 + k];
    sg += lng[k]*kv; sb += lnb[k]*kv;
  }
  #pragma unroll
  for (int d=1; d<64; d<<=1){ sg += __shfl_xor(sg, d); sb += __shfl_xor(sb, d); }
  if (lane == 0){ GB[n] = sg; BeB[n] = sb; }
}

// ---------------- per-batch: mask/logdur outputs, exact lower median --------
__global__ __launch_bounds__(1024) void k_median(
    const float* __restrict__ dur, const float* __restrict__ msk,
    float* __restrict__ out, float* __restrict__ supp_f){
  __shared__ u32 keys[4096];
  __shared__ u32 hist[2048];
  __shared__ float sred[1024];
  __shared__ u32 selBin, selRank;
  __shared__ float sMed;
  const int tid = threadIdx.x;
  const int b = blockIdx.x;
  float msum = 0.f;
  for (int i = tid; i < 4096; i += 1024){
    int bt = (b << 12) + i;
    float m  = clip01(msk[bt]);
    float ld = logf(fmaxf(dur[bt], 1e-4f)) * m;
    out[O_MASK + bt] = m;
    out[O_LOGD + bt] = ld;
    u32 u = __float_as_uint(ld);
    u32 k = (u & 0x80000000u) ? ~u : (u | 0x80000000u);
    keys[i] = (m > 0.5f) ? k : 0xFFFFFFFFu;
    msum += m;
  }
  sred[tid] = msum;
  __syncthreads();
  for (int s = 512; s > 0; s >>= 1){
    if (tid < s) sred[tid] += sred[tid + s];
    __syncthreads();
  }
  float msumT = sred[0];
  int cnt = (int)(msumT + 0.5f);
  u32 prefix = 0;
  u32 r = (cnt > 0) ? (u32)((cnt - 1) >> 1) : 0u;
  if (cnt > 0){
    #pragma unroll
    for (int p = 0; p < 3; ++p){
      const int shift = (p==0) ? 21 : (p==1) ? 10 : 0;
      const int nb = (p==2) ? 1024 : 2048;
      const u32 himask = (p==0) ? 0u : (0xFFFFFFFFu << (shift + ((p==2)?10:11)));
      hist[tid] = 0u; hist[tid + 1024] = 0u;
      __syncthreads();
      for (int i = tid; i < 4096; i += 1024){
        u32 k = keys[i];
        if ((k & himask) == prefix)
          atomicAdd(&hist[(k >> shift) & (u32)(nb-1)], 1u);
      }
      __syncthreads();
      if (tid < 64){
        u32 lane = tid;
        u32 cum = 0;
        for (int chunk = 0; chunk < nb/64; ++chunk){
          u32 v = hist[chunk*64 + lane];
          u32 incl = v;
          #pragma unroll
          for (int d = 1; d < 64; d <<= 1){
            u32 o = __shfl_up(incl, d);
            if (lane >= (u32)d) incl += o;
          }
          u32 total = __shfl(incl, 63);
          if (r < cum + total){
            u32 excl = incl - v;
            bool hit = (r >= cum + excl) && (r < cum + excl + v);
            unsigned long long bal = __ballot(hit);
            int L = __ffsll((unsigned long long)bal) - 1;
            u32 exclL = __shfl(excl, L);
            if (lane == 0){ selBin = (u32)(chunk*64 + L); selRank = r - (cum + exclL); }
            break;
          }
          cum += total;
        }
      }
      __syncthreads();
      prefix |= (selBin << shift);
      r = selRank;
      __syncthreads();
    }
  }
  if (tid == 0){
    float med = 0.f;
    if (cnt > 0){
      u32 k = prefix;
      u32 u = (k & 0x80000000u) ? (k ^ 0x80000000u) : ~k;
      med = __uint_as_float(u);
    }
    out[O_RATE + b] = med;
    supp_f[b] = fmaxf(msumT, 1.0f);
    sMed = med;
  }
  __syncthreads();
  float med = sMed;
  for (int i = tid; i < 4096; i += 1024){
    int bt = (b << 12) + i;
    float m  = clip01(msk[bt]);
    float ld = logf(fmaxf(dur[bt], 1e-4f)) * m;
    out[O_RESID + bt] = (ld - med) * m;
  }
}

// ---------------- embedding + aux proj -> h0 [g][t] (coalesced writes) ------
__global__ __launch_bounds__(256) void k_embed(
    const int* __restrict__ units, const float* __restrict__ dur,
    const float* __restrict__ msk, const float* __restrict__ emb,
    const float* __restrict__ pw, const float* __restrict__ pb,
    u16* __restrict__ h0, int b0){
  int wid = threadIdx.x >> 6, lane = threadIdx.x & 63;
  int w = blockIdx.x*4 + wid;           // over C*64g*64tb
  int tb = w & 63, g = (w >> 6) & 63, lb = w >> 12;
  int t = tb*64 + lane;
  int bt = ((b0 + lb) << 12) + t;
  float m = clip01(msk[bt]);
  float ld = logf(fmaxf(dur[bt], 1e-4f)) * m;
  long u = units[bt];
  const float* er = emb + u*512 + g*8;
  float4 e0 = *(const float4*)er;
  float4 e1 = *(const float4*)(er + 4);
  float x[8] = {e0.x,e0.y,e0.z,e0.w,e1.x,e1.y,e1.z,e1.w};
  union { u16 s[8]; uint4 v; } o;
  #pragma unroll
  for (int j=0;j<8;++j)
    o.s[j] = f2b(x[j] + ld*pw[(g*8+j)*4] + pb[g*8+j]);
  *(uint4*)(h0 + ((long)(lb*64 + g)*TP_ + 2 + t)*8) = o.v;
}

// ---------------- causal conv (K=3) MFMA GEMM -------------------------------
// 256x256 tile, R1's proven 2-barrier-per-kt schedule, but 1024 threads:
// 16 waves (4M x 4N, wave-tile 64x64, acc[4][4]) -> 4 waves/SIMD in the one
// LDS-limited block (vs 2 waves/SIMD at 512thr). Fills ds_read->MFMA
// dependency gaps with TLP. Stages: 4 loads/thread (+1 halo tid<8),
// counted s_waitcnt vmcnt(4) (never 0 mid-loop).
// LDS granule map: A0 [0,1032) A1 [1032,2064) B0 [2064,5136) B1 [5136,8208)
// A: [gcol4][row258]; B: [tap3][g4][col256].
__device__ __forceinline__ void stageA(u16* smem, const u16* hin, long aG, int t0,
                                       int tid, int kt, int base){
  { int s = tid;                             // 0..1023 of 1032
    int gl = s / 258, row = s - gl*258;
    cp16(hin + (aG + (long)(kt*4 + gl)*TP_ + t0 + row)*8, &smem[(base + s)*8]); }
  if (tid < 8){
    int s = 1024 + tid;                      // gl = 3, row = s - 774
    cp16(hin + (aG + (long)(kt*4 + 3)*TP_ + t0 + (s - 774))*8, &smem[(base + s)*8]);
  }
}
__device__ __forceinline__ void stageB(u16* smem, const u16* w, int n0,
                                       int tid, int kt, int base){
  #pragma unroll
  for (int q = 0; q < 3; ++q){
    int s2 = q*1024 + tid;
    int tap = s2 >> 10, g = (s2 >> 8) & 3, col = s2 & 255;
    cp16(w + ((long)((tap*16 + kt)*4 + g)*512 + n0 + col)*8, &smem[(base + s2)*8]);
  }
}

template<int STATS>
__global__ __launch_bounds__(1024, 4) void k_conv(const u16* __restrict__ hin,
                                                  const u16* __restrict__ wrp2c,
                                                  const float* __restrict__ bias,
                                                  u16* __restrict__ hout,
                                                  float* __restrict__ rsum,
                                                  float* __restrict__ rsumsq,
                                                  int statsBase, int nwg){
  __shared__ __align__(16) u16 smem[65664];   // 8208 granules (131,328 B)
  const int tid = threadIdx.x;
  const int lane = tid & 63, wid = tid >> 6;  // wid 0..15
  const int wm = wid >> 2, wn = wid & 3;      // 4M x 4N waves
  const int g4 = lane >> 4, r16 = lane & 15;
  // XCD-chunked bijective swizzle (nwg % 8 == 0 always: nwg = C*32)
  const int cpx = nwg >> 3;
  const int wg  = ((int)blockIdx.x & 7)*cpx + ((int)blockIdx.x >> 3);
  const int nt = wg & 1, mt = wg >> 1;
  const int lb = mt >> 4, t0 = (mt & 15) << 8;
  const int n0 = nt << 8;
  const long aG = (long)lb*64*TP_;

  fx4 acc[4][4];
  #pragma unroll
  for (int i=0;i<4;++i)
    #pragma unroll
    for (int j=0;j<4;++j){ acc[i][j][0]=0.f; acc[i][j][1]=0.f; acc[i][j][2]=0.f; acc[i][j][3]=0.f; }

  // prologue: stage kt=0 into buffer 0 (B first, then A — matches in-loop order)
  stageB(smem, wrp2c, n0, tid, 0, 2064);
  stageA(smem, hin, aG, t0, tid, 0, 0);

  int cur = 0;
  #pragma unroll 1
  for (int kt = 0; kt < 16; ++kt){
    if (kt < 15){
      // issue next K-step stages (B 3/thread, A 1-2/thread)
      stageB(smem, wrp2c, n0, tid, kt+1, 2064 + (cur^1)*3072);
      stageA(smem, hin, aG, t0, tid, kt+1, (cur^1)*1032);
      // drain previous tile's loads; keep this iteration's 4 newest in flight
      asm volatile("s_waitcnt vmcnt(4)" ::: "memory");
    } else {
      asm volatile("s_waitcnt vmcnt(0)" ::: "memory");
    }
    __builtin_amdgcn_s_barrier();
    __builtin_amdgcn_sched_barrier(0);
    {
      const u16* Ab = &smem[cur*1032*8];
      const u16* Bb = &smem[(2064 + cur*3072)*8];
      #pragma unroll
      for (int tap = 0; tap < 3; ++tap){
        bf16x8 af[4], bf[4];
        #pragma unroll
        for (int mi=0;mi<4;++mi)
          af[mi] = *(const bf16x8*)&Ab[(g4*258 + wm*64 + mi*16 + r16 + tap)*8];
        #pragma unroll
        for (int ni=0;ni<4;++ni)
          bf[ni] = *(const bf16x8*)&Bb[(tap*1024 + g4*256 + wn*64 + ni*16 + r16)*8];
        __builtin_amdgcn_s_setprio(1);
        #pragma unroll
        for (int mi=0;mi<4;++mi)
          #pragma unroll
          for (int ni=0;ni<4;++ni)
            acc[mi][ni] = __builtin_amdgcn_mfma_f32_16x16x32_bf16(af[mi], bf[ni], acc[mi][ni], 0,0,0);
        __builtin_amdgcn_s_setprio(0);
      }
    }
    __builtin_amdgcn_sched_barrier(0);
    __builtin_amdgcn_s_barrier();
    cur ^= 1;
  }

  // epilogue: bias + gelu (+stats), then LDS transpose -> coalesced [g][t] stores
  __builtin_amdgcn_sched_barrier(0);
  const int cl = r16;
  float bv[4];
  #pragma unroll
  for (int ni=0;ni<4;++ni) bv[ni] = bias[n0 + wn*64 + ni*16 + cl];
  #pragma unroll
  for (int mi=0;mi<4;++mi)
    #pragma unroll
    for (int rg=0;rg<4;++rg){
      int r = wm*64 + mi*16 + g4*4 + rg;
      float sv = 0.f, sv2 = 0.f;
      #pragma unroll
      for (int ni=0;ni<4;++ni){
        float v = gelu_f(acc[mi][ni][rg] + bv[ni]);
        int c = wn*64 + ni*16 + cl;
        smem[(c >> 3)*2048 + r*8 + (c & 7)] = f2b(v);
        if (STATS){ sv += v; sv2 += v*v; }
      }
      if (STATS){
        #pragma unroll
        for (int d=1; d<16; d<<=1){ sv += __shfl_xor(sv, d); sv2 += __shfl_xor(sv2, d); }
        if (cl == 0){
          int grow = statsBase + lb*4096 + t0 + r;
          atomicAdd(&rsum[grow], sv);
          atomicAdd(&rsumsq[grow], sv2);
        }
      }
    }
  __syncthreads();
  #pragma unroll
  for (int it = 0; it < 8; ++it){
    int s = it*1024 + tid;
    int gc = s >> 8, row = s & 255;
    long gran = aG + (long)(nt*32 + gc)*TP_ + 2 + t0 + row;
    *(uint4*)(hout + gran*8) = *(const uint4*)&smem[gc*2048 + row*8];
  }
}

// -------- score GEMM (LN fused as affine) + softmax + attn + S-reductions ---
// 512 thr / 8 waves (2M x 4N, wave = 64x64), double-buffered A+B staging,
// counted vmcnt(3), setprio, XCD swizzle. A/B LDS strides padded (130/260
// granules). Attn output staged through a padded fp32 LDS buffer ->
// fully-coalesced float4 stores (1KB/wave).
__global__ __launch_bounds__(512, 4) void k_score(const u16* __restrict__ h,
                                                  const u16* __restrict__ rkb,
                                                  const float* __restrict__ msk,
                                                  const float* __restrict__ rsum,
                                                  const float* __restrict__ rsumsq,
                                                  const float* __restrict__ GB,
                                                  const float* __restrict__ BeB,
                                                  float* __restrict__ S0,
                                                  float* __restrict__ S1,
                                                  float* __restrict__ S2,
                                                  float* __restrict__ out, int b0){
  __shared__ __align__(16) u16 smem[24960];   // 3120 granules: A 2x520, B 2x1040
  __shared__ float smax[128][4];
  __shared__ float ssum[128][4];
  const int tid = threadIdx.x;
  const int lane = tid & 63, wid = tid >> 6;
  const int wm = wid >> 2, wn = wid & 3;      // 2M x 4N waves
  const int g4 = lane >> 4, r16 = lane & 15;
  // XCD-chunked bijective swizzle over row-tiles (gridDim.x % 8 == 0)
  const int cpx = (int)gridDim.x >> 3;
  const int wg  = ((int)blockIdx.x & 7)*cpx + ((int)blockIdx.x >> 3);
  const int r0 = wg << 7;
  const int lb = r0 >> 12, t0 = r0 & 4095;
  const int gb = b0 + lb;
  const long gRow0 = ((long)gb << 12) + t0;
  const long aG = (long)lb*64*TP_;

  fx4 acc[4][4];
  #pragma unroll
  for (int i=0;i<4;++i)
    #pragma unroll
    for (int j=0;j<4;++j){ acc[i][j][0]=0.f; acc[i][j][1]=0.f; acc[i][j][2]=0.f; acc[i][j][3]=0.f; }

  // stage tile kt into buffer buf: A 1/thread + B 2/thread = 3 VMEM per thread
  // A lds: [g4][row128 pad->130]; B lds: [g4][col256 pad->260]
  #define SC_STAGE(kt, buf) do {                                               \
    int s = tid; int gl = s >> 7, row = s & 127;                               \
    cp16(h + (aG + (long)((kt)*4 + gl)*TP_ + 2 + t0 + row)*8,                  \
         &smem[((buf)*520 + gl*130 + row)*8]);                                 \
    _Pragma("unroll")                                                          \
    for (int q = 0; q < 2; ++q){                                               \
      int s2 = q*512 + tid;                                                    \
      int g = s2 >> 8, col = s2 & 255;                                         \
      cp16(rkb + ((long)(kt)*1024 + s2)*8,                                     \
           &smem[(1040 + (buf)*1040 + g*260 + col)*8]);                        \
    } } while(0)

  SC_STAGE(0, 0);
  #pragma unroll 1
  for (int kt = 0; kt < 16; ++kt){
    const int cur = kt & 1;
    if (kt < 15){
      SC_STAGE(kt+1, cur^1);
      asm volatile("s_waitcnt vmcnt(3)" ::: "memory");
    } else {
      asm volatile("s_waitcnt vmcnt(0)" ::: "memory");
    }
    __builtin_amdgcn_s_barrier();
    __builtin_amdgcn_sched_barrier(0);
    {
      const u16* Ab = &smem[(cur*520)*8];
      const u16* Bb = &smem[(1040 + cur*1040)*8];
      bf16x8 af[4], bf[4];
      #pragma unroll
      for (int mi=0;mi<4;++mi)
        af[mi] = *(const bf16x8*)&Ab[(g4*130 + wm*64 + mi*16 + r16)*8];
      #pragma unroll
      for (int ni=0;ni<4;++ni)
        bf[ni] = *(const bf16x8*)&Bb[(g4*260 + wn*64 + ni*16 + r16)*8];
      __builtin_amdgcn_s_setprio(1);
      #pragma unroll
      for (int mi=0;mi<4;++mi)
        #pragma unroll
        for (int ni=0;ni<4;++ni)
          acc[mi][ni] = __builtin_amdgcn_mfma_f32_16x16x32_bf16(af[mi], bf[ni], acc[mi][ni], 0,0,0);
      __builtin_amdgcn_s_setprio(0);
    }
    __builtin_amdgcn_sched_barrier(0);
    __builtin_amdgcn_s_barrier();
  }
  #undef SC_STAGE

  const float SCALE = 0.044194173824159216f;   // 1/sqrt(512)
  const int cl = r16;
  float gbv[4], bbv[4];
  #pragma unroll
  for (int ni=0;ni<4;++ni){
    int col = wn*64 + ni*16 + cl;
    gbv[ni] = GB[col]; bbv[ni] = BeB[col];
  }
  float gmx[4][4];
  #pragma unroll
  for (int mi=0;mi<4;++mi)
    #pragma unroll
    for (int rg=0;rg<4;++rg){
      int row = wm*64 + mi*16 + g4*4 + rg;
      long gRow = gRow0 + row;
      float mk = clip01(msk[gRow]);
      float mu = rsum[gRow] * (1.f/512.f);
      float var = rsumsq[gRow] * (1.f/512.f) - mu*mu;
      float inv = rsqrtf(var + 1e-5f);
      float mx = -1e30f;
      #pragma unroll
      for (int ni=0;ni<4;++ni){
        float s = mk * SCALE * (inv*(acc[mi][ni][rg] - mu*gbv[ni]) + bbv[ni]);
        acc[mi][ni][rg] = s;
        mx = fmaxf(mx, s);
      }
      #pragma unroll
      for (int d=1; d<16; d<<=1) mx = fmaxf(mx, __shfl_xor(mx, d));
      if (cl == 0) smax[row][wn] = mx;
    }
  __syncthreads();
  #pragma unroll
  for (int mi=0;mi<4;++mi)
    #pragma unroll
    for (int rg=0;rg<4;++rg){
      int row = wm*64 + mi*16 + g4*4 + rg;
      gmx[mi][rg] = fmaxf(fmaxf(smax[row][0], smax[row][1]),
                          fmaxf(smax[row][2], smax[row][3]));
    }
  #pragma unroll
  for (int mi=0;mi<4;++mi)
    #pragma unroll
    for (int rg=0;rg<4;++rg){
      float s = 0.f;
      #pragma unroll
      for (int ni=0;ni<4;++ni){
        float e = expf(acc[mi][ni][rg] - gmx[mi][rg]);
        acc[mi][ni][rg] = e;
        s += e;
      }
      #pragma unroll
      for (int d=1; d<16; d<<=1) s += __shfl_xor(s, d);
      if (cl == 0) ssum[wm*64 + mi*16 + g4*4 + rg][wn] = s;
    }
  __syncthreads();
  // ---- attn epilogue: per-mi 32x256 chunk through padded LDS fp32 buffer ---
  float* fbuf = (float*)smem;                 // 32 x 260 floats = 33,280 B
  float ps0[4], ps1[4], ps2[4];
  #pragma unroll
  for (int ni=0;ni<4;++ni){ ps0[ni]=0.f; ps1[ni]=0.f; ps2[ni]=0.f; }
  #pragma unroll
  for (int mi=0;mi<4;++mi){
    __syncthreads();                          // fbuf free (prev flush done)
    #pragma unroll
    for (int rg=0;rg<4;++rg){
      int row = wm*64 + mi*16 + g4*4 + rg;
      long gRow = gRow0 + row;
      float tot = (ssum[row][0] + ssum[row][1]) + (ssum[row][2] + ssum[row][3]);
      float mk = clip01(msk[gRow]);
      float f = mk / tot;
      float rr = out[O_RESID + gRow];
      #pragma unroll
      for (int ni=0;ni<4;++ni){
        float a = acc[mi][ni][rg] * f;
        fbuf[(wm*16 + g4*4 + rg)*260 + wn*64 + ni*16 + cl] = a;
        ps0[ni] += a; ps1[ni] += a*rr; ps2[ni] += a*rr*rr;
      }
    }
    __syncthreads();
    #pragma unroll
    for (int p=0;p<4;++p){
      int lrow = p*8 + (tid >> 6);            // one row per wave per pass
      int c4 = tid & 63;
      float4 v = *(const float4*)&fbuf[lrow*260 + c4*4];
      int grow = (lrow >> 4)*64 + mi*16 + (lrow & 15);
      *(float4*)(out + O_ATTN + (gRow0 + grow)*M_ + c4*4) = v;
    }
  }
  #pragma unroll
  for (int ni=0;ni<4;++ni){
    ps0[ni] += __shfl_xor(ps0[ni], 16); ps0[ni] += __shfl_xor(ps0[ni], 32);
    ps1[ni] += __shfl_xor(ps1[ni], 16); ps1[ni] += __shfl_xor(ps1[ni], 32);
    ps2[ni] += __shfl_xor(ps2[ni], 16); ps2[ni] += __shfl_xor(ps2[ni], 32);
  }
  if (g4 == 0){
    #pragma unroll
    for (int ni=0;ni<4;++ni){
      int col = wn*64 + ni*16 + cl;
      atomicAdd(&S0[gb*M_ + col], ps0[ni]);
      atomicAdd(&S1[gb*M_ + col], ps1[ni]);
      atomicAdd(&S2[gb*M_ + col], ps2[ni]);
    }
  }
}

// ---------------- finalize role_value / role_var / role_cov -----------------
__global__ __launch_bounds__(256) void k_final(const float* __restrict__ S0,
                                               const float* __restrict__ S1,
                                               const float* __restrict__ S2,
                                               const float* __restrict__ supp,
                                               float* __restrict__ out,
                                               float* __restrict__ rvf){
  int i = blockIdx.x*256 + threadIdx.x;   // 4096
  int b = i >> 8;
  float s0 = S0[i], s1 = S1[i], s2 = S2[i];
  float cov = fmaxf(s0, 1e-6f);
  float rv = s1 / cov;
  float var = fmaxf((s2 - 2.f*rv*s1 + rv*rv*s0) / cov, 1e-4f);
  float rc = fmaxf(cov / supp[b], 0.05f);
  out[O_RVAL + i] = rv;
  out[O_RVAR + i] = var;
  out[O_RCOV + i] = rc;
  rvf[i] = rv;
}

// ---------------- prompt_role_fit = (attn . role_value) * mask --------------
__global__ __launch_bounds__(256) void k_fit(const float* __restrict__ attn,
                                             const float* __restrict__ rvf,
                                             const float* __restrict__ msk,
                                             float* __restrict__ out){
  int wid = threadIdx.x >> 6, lane = threadIdx.x & 63;
  int row = blockIdx.x*4 + wid;
  int b = row >> 12;
  float4 a = *(const float4*)(attn + (long)row*M_ + lane*4);
  float4 r = *(const float4*)(rvf + b*M_ + lane*4);
  float dot = a.x*r.x + a.y*r.y + a.z*r.z + a.w*r.w;
  #pragma unroll
  for (int d=1; d<64; d<<=1) dot += __shfl_xor(dot, d);
  if (lane == 0) out[O_FIT + row] = dot * clip01(msk[row]);
}

// ---------------- launcher --------------------------------------------------
extern "C" void kernel_launch(void* const* d_in, const int* in_sizes, int n_in,
                              void* d_out, int out_size, void* d_ws, size_t ws_size,
                              hipStream_t stream) {
  const int*   units = (const int*)d_in[0];
  const float* dur   = (const float*)d_in[1];
  const float* msk   = (const float*)d_in[2];
  const float* emb   = (const float*)d_in[3];
  const float* pw    = (const float*)d_in[4];
  const float* pb    = (const float*)d_in[5];
  const float* w1    = (const float*)d_in[6];
  const float* b1    = (const float*)d_in[7];
  const float* w2    = (const float*)d_in[8];
  const float* b2c   = (const float*)d_in[9];
  const float* lng   = (const float*)d_in[10];
  const float* lnb   = (const float*)d_in[11];
  const float* rk    = (const float*)d_in[12];
  float* out = (float*)d_out;
  char* ws = (char*)d_ws;

  // conv1 output lives in the (dead-until-k_score) attn+fit region of d_out
  u16* hA = (u16*)(out + O_ATTN);

  const size_t perB = (size_t)64*TP_*16;               // 4,196,352 B per batch
  const size_t tail = 3145728 + 262144 + 1024 + 1024 + 64 + 16384 + 49152 + 262144 + 262144;
  int C = 16;
  while (C > 1 && ((size_t)C*perB + tail) > ws_size) C >>= 1;
  const int nch = 16 / C;

  char* p = ws;
  u16*   h0    = (u16*)p;            p += (size_t)C*perB;
  u16*   wrp2  = (u16*)p;            p += 3145728;
  u16*   rkb   = (u16*)p;            p += 262144;
  float* GB    = (float*)p;          p += 1024;
  float* BeB   = (float*)p;          p += 1024;
  float* supp_f= (float*)p;          p += 64;
  float* rv_f  = (float*)p;          p += 16384;
  float* S0    = (float*)p;          p += 49152;  // S0,S1,S2
  float* S1    = S0 + 4096;
  float* S2    = S1 + 4096;
  float* rsum  = (float*)p;          p += 262144;
  float* rsumsq= (float*)p;          p += 262144;

  hipMemsetAsync(S0, 0, 49152 + 262144 + 262144, stream);
  int initN = (C << 7) + 2048 + 128;
  k_init  <<<(initN + 255)/256, 256, 0, stream>>>(h0, hA, C, out);
  k_repack<<<6656, 256, 0, stream>>>(w1, w2, rk, lng, wrp2, rkb);
  k_gbb   <<<256,   64, 0, stream>>>(rk, lng, lnb, GB, BeB);
  k_median<<<16,  1024, 0, stream>>>(dur, msk, out, supp_f);
  const int nwg = C*32;
  for (int c = 0; c < nch; ++c){
    int b0 = c*C;
    u16* hAc = hA + (size_t)b0*64*TP_*8;
    k_embed  <<<C*1024, 256, 0, stream>>>(units, dur, msk, emb, pw, pb, h0, b0);
    k_conv<0><<<nwg,   1024, 0, stream>>>(h0,  wrp2,           b1,  hAc, rsum, rsumsq, 0,       nwg);
    k_conv<1><<<nwg,   1024, 0, stream>>>(hAc, wrp2 + 786432,  b2c, h0,  rsum, rsumsq, b0*4096, nwg);
    k_score  <<<nwg,    512, 0, stream>>>(h0, rkb, msk, rsum, rsumsq, GB, BeB, S0, S1, S2, out, b0);
  }
  k_final <<<16,    256, 0, stream>>>(S0, S1, S2, supp_f, out, rv_f);
  k_fit   <<<16384, 256, 0, stream>>>(out + O_ATTN, rv_f, msk, out);
}